// Round 3
// baseline (2086.370 us; speedup 1.0000x reference)
//
#include <hip/hip_runtime.h>
#include <hip/hip_bf16.h>

#define Hn   89
#define Tn   120
#define BM   64
#define LDP  104   // LDS row pitch (bf16): 208B -> 16B-aligned rows, mild bank rotation
#define NTHR 512   // 8 waves: 6 compute (j-tiles 0..5) + 2 producers (X staging)
#define NCMP 384

using bf16   = __bf16;
using bf16x8 = __attribute__((ext_vector_type(8))) __bf16;
typedef __attribute__((ext_vector_type(4))) float f32x4;

__device__ __forceinline__ f32x4 ld4(const float* p) {   // 4B-aligned 16B load
  f32x4 v; __builtin_memcpy(&v, p, 16); return v;
}
__device__ __forceinline__ bf16x8 pack8(f32x4 a, f32x4 b) {
  bf16x8 r;
  r[0]=(bf16)a[0]; r[1]=(bf16)a[1]; r[2]=(bf16)a[2]; r[3]=(bf16)a[3];
  r[4]=(bf16)b[0]; r[5]=(bf16)b[1]; r[6]=(bf16)b[2]; r[7]=(bf16)b[3];
  return r;
}
__device__ __forceinline__ float fsig(float x) {
  return __builtin_amdgcn_rcpf(1.f + __builtin_amdgcn_exp2f(-1.44269504f * x));
}
__device__ __forceinline__ float ftanh(float x) {
  return 1.f - 2.f * __builtin_amdgcn_rcpf(1.f + __builtin_amdgcn_exp2f(2.88539008f * x));
}

// 8-wave persistent block over 64 batch rows x 120 steps.
// Compute wave w<6 owns j-slice [16w,16w+16); weights live in registers.
// Producer waves 6,7: global->reg->LDS X staging (issue-early/commit-late).
// One barrier/step: { H(t),X(t) -> buf[t&1]; issue X(t+1); BAR; MFMA+gates }.
// Biases folded via constant-1.0 column at k=89 (X col89=1.0 each step,
// H col89=1.0 persistent). r/z use merged i+h accumulators.
__global__ __launch_bounds__(NTHR, 4)
void gru_fused(const float* __restrict__ X,    // [B][T][89]
               const float* __restrict__ Wih,  // [267][89]
               const float* __restrict__ Whh,  // [267][89]
               const float* __restrict__ bih,  // [267]
               const float* __restrict__ bhh,  // [267]
               const float* __restrict__ Wm,   // [32][89]
               const float* __restrict__ bm,   // [32]
               const float* __restrict__ Wo,   // [32]
               const float* __restrict__ bo,   // [1]
               float* __restrict__ Y,          // [B] mscore | [B][32] mmetric
               int Bt)
{
  __shared__ __align__(16) bf16 Xl[2][BM][LDP];
  __shared__ __align__(16) bf16 Hl[2][BM][LDP];
  __shared__ float Ml[BM][32];

  const int tid  = threadIdx.x;
  const int lane = tid & 63;
  const int wv   = tid >> 6;
  const int l15  = lane & 15;
  const int kg   = lane >> 4;             // 0..3
  const int j    = wv * 16 + l15;         // meaningful for wv<6
  const bool cmp = (wv < 6);
  const bool jok = cmp && (j < Hn);       // j==89 is the constant-1 column
  const size_t brow0 = (size_t)blockIdx.x * BM;

  // ---- weights -> persistent register B-frags; k==89 carries biases ----
  bf16x8 Bf[3][2][3];
#pragma unroll
  for (int g = 0; g < 3; ++g)
#pragma unroll
    for (int s = 0; s < 2; ++s) {
      const float* W = s ? Whh : Wih;
#pragma unroll
      for (int kt = 0; kt < 3; ++kt) {
        bf16x8 f;
        const int k0 = kt * 32 + kg * 8;
#pragma unroll
        for (int e = 0; e < 8; ++e) {
          const int k = k0 + e;
          float v = 0.f;
          if (jok) {
            if (k < Hn) v = W[(size_t)(g * Hn + j) * Hn + k];
            else if (k == Hn) {
              if (g < 2) v = s ? 0.f : (bih[g * Hn + j] + bhh[g * Hn + j]);
              else       v = s ? bhh[2 * Hn + j] : bih[2 * Hn + j];
            }
          }
          f[e] = (bf16)v;
        }
        Bf[g][s][kt] = f;
      }
    }

  // ---- producer setup: 128 threads, thread = (row, half of 48 cols) ----
  const int ptid  = tid & 127;            // valid only for wv>=6
  const int prow  = ptid & 63;
  const int phalf = (ptid >> 6) & 1;      // wave-uniform (wave6=0, wave7=1)
  const float* Xrow = X + (brow0 + prow) * (size_t)(Tn * Hn) + phalf * 48;

  f32x4 v0, v1, v2, v3, v4, v5, v6, v7, v8, v9, v10, v11;  // named: spill-proof
  float vs = 0.f;

  auto pissue = [&](int toff) {
    const float* bp = Xrow + toff;
    if (phalf == 0) {
      v0 = ld4(bp);      v1 = ld4(bp + 4);  v2 = ld4(bp + 8);  v3 = ld4(bp + 12);
      v4 = ld4(bp + 16); v5 = ld4(bp + 20); v6 = ld4(bp + 24); v7 = ld4(bp + 28);
      v8 = ld4(bp + 32); v9 = ld4(bp + 36); v10 = ld4(bp + 40); v11 = ld4(bp + 44);
    } else {            // cols 48..88 real; 89 = 1.0; 90..95 = 0
      v0 = ld4(bp);      v1 = ld4(bp + 4);  v2 = ld4(bp + 8);  v3 = ld4(bp + 12);
      v4 = ld4(bp + 16); v5 = ld4(bp + 20); v6 = ld4(bp + 24); v7 = ld4(bp + 28);
      v8 = ld4(bp + 32); v9 = ld4(bp + 36); vs = bp[40];
    }
  };
  auto pcommit = [&](int b) {
    bf16x8* dst = (bf16x8*)&Xl[b][prow][phalf * 48];
    dst[0] = pack8(v0, v1); dst[1] = pack8(v2, v3); dst[2] = pack8(v4, v5);
    dst[3] = pack8(v6, v7); dst[4] = pack8(v8, v9);
    if (phalf == 0) dst[5] = pack8(v10, v11);
    else {
      f32x4 ta = {vs, 1.0f, 0.f, 0.f}, tb = {0.f, 0.f, 0.f, 0.f};
      dst[5] = pack8(ta, tb);
    }
  };

  // ---- init: H pad cols (both bufs): col89 = 1.0, 90..95 = 0 ----
  if (tid < 128) {
    const int bb = tid >> 6, r = tid & 63;
    Hl[bb][r][89] = (bf16)1.0f;
#pragma unroll
    for (int c = 90; c < 96; ++c) Hl[bb][r][c] = (bf16)0.f;
  }

  float hold[4][4];
#pragma unroll
  for (int mt = 0; mt < 4; ++mt)
#pragma unroll
    for (int q = 0; q < 4; ++q) hold[mt][q] = 0.f;

  if (!cmp) pissue(0);

  bf16*       hwb = &Hl[0][0][0] + (kg * 4) * LDP + j;
  const bf16* xrb = &Xl[0][0][0] + l15 * LDP + kg * 8;
  const bf16* hrb = &Hl[0][0][0] + l15 * LDP + kg * 8;
  const int bufo = BM * LDP;

  int toff = 0;
  for (int t = 0; t < Tn; ++t) {
    const int b = t & 1;
    if (cmp) {
      if (jok) {                       // write h(t) -> buf b (h(0)=0)
        bf16* hw = hwb + b * bufo;
#pragma unroll
        for (int mt = 0; mt < 4; ++mt)
#pragma unroll
          for (int q = 0; q < 4; ++q)
            hw[(mt * 16 + q) * LDP] = (bf16)hold[mt][q];
      }
    } else {
      pcommit(b);                      // X(t) regs -> buf b
      toff += Hn;
      if (t + 1 < Tn) pissue(toff);    // X(t+1) -> regs (lands under this step)
    }
    __syncthreads();

    if (cmp) {
      __builtin_amdgcn_s_setprio(1);
      const bf16* xr = xrb + b * bufo;
      const bf16* hr = hrb + b * bufo;
#pragma unroll
      for (int mt = 0; mt < 4; ++mt) {
        f32x4 ar = {0,0,0,0}, az = {0,0,0,0}, ain = {0,0,0,0}, ahn = {0,0,0,0};
#pragma unroll
        for (int kt = 0; kt < 3; ++kt) {
          const bf16x8 ax = *(const bf16x8*)(xr + mt * 16 * LDP + kt * 32);
          const bf16x8 ah = *(const bf16x8*)(hr + mt * 16 * LDP + kt * 32);
          ar  = __builtin_amdgcn_mfma_f32_16x16x32_bf16(ax, Bf[0][0][kt], ar, 0, 0, 0);
          ar  = __builtin_amdgcn_mfma_f32_16x16x32_bf16(ah, Bf[0][1][kt], ar, 0, 0, 0);
          az  = __builtin_amdgcn_mfma_f32_16x16x32_bf16(ax, Bf[1][0][kt], az, 0, 0, 0);
          az  = __builtin_amdgcn_mfma_f32_16x16x32_bf16(ah, Bf[1][1][kt], az, 0, 0, 0);
          ain = __builtin_amdgcn_mfma_f32_16x16x32_bf16(ax, Bf[2][0][kt], ain, 0, 0, 0);
          ahn = __builtin_amdgcn_mfma_f32_16x16x32_bf16(ah, Bf[2][1][kt], ahn, 0, 0, 0);
        }
#pragma unroll
        for (int q = 0; q < 4; ++q) {
          const float r_ = fsig(ar[q]);
          const float z_ = fsig(az[q]);
          const float n_ = ftanh(ain[q] + r_ * ahn[q]);
          hold[mt][q] = n_ + z_ * (hold[mt][q] - n_);
        }
      }
      __builtin_amdgcn_s_setprio(0);
    }
  }

  // ---- final h -> Hl[0] (consume(119) read buf1; buf0 is free) ----
  if (jok) {
#pragma unroll
    for (int mt = 0; mt < 4; ++mt)
#pragma unroll
      for (int q = 0; q < 4; ++q)
        hwb[(mt * 16 + q) * LDP] = (bf16)hold[mt][q];
  }
  __syncthreads();

  // ---- epilogue: metric_fc (89->32, sigmoid), output_fc (32->1, sigmoid) ----
  const bf16* Hf = &Hl[0][0][0];
  for (int p = tid; p < BM * 32; p += NTHR) {
    const int r = p >> 5, c = p & 31;
    float acc = bm[c];
    const bf16* hr2 = Hf + r * LDP;
    for (int k = 0; k < Hn; ++k) acc = fmaf((float)hr2[k], Wm[c * Hn + k], acc);
    const float mv = fsig(acc);
    Ml[r][c] = mv;
    Y[(size_t)Bt + (brow0 + r) * 32 + c] = mv;   // out_mmetric
  }
  __syncthreads();
  if (tid < BM) {
    float acc = bo[0];
#pragma unroll
    for (int c = 0; c < 32; ++c) acc = fmaf(Ml[tid][c], Wo[c], acc);
    Y[brow0 + tid] = fsig(acc);                  // out_mscore
  }
}

extern "C" void kernel_launch(void* const* d_in, const int* in_sizes, int n_in,
                              void* d_out, int out_size, void* d_ws, size_t ws_size,
                              hipStream_t stream) {
  const float* X   = (const float*)d_in[0];
  const float* Wih = (const float*)d_in[1];
  const float* Whh = (const float*)d_in[2];
  const float* bih = (const float*)d_in[3];
  const float* bhh = (const float*)d_in[4];
  const float* Wm  = (const float*)d_in[5];
  const float* bm  = (const float*)d_in[6];
  const float* Wo  = (const float*)d_in[7];
  const float* bo  = (const float*)d_in[8];

  const int B = in_sizes[0] / (Tn * Hn);   // 32768
  dim3 grid(B / BM), block(NTHR);
  gru_fused<<<grid, block, 0, stream>>>(X, Wih, Whh, bih, bhh, Wm, bm, Wo, bo,
                                        (float*)d_out, B);
}

// Round 4
// 728.181 us; speedup vs baseline: 2.8652x; 2.8652x over previous
//
#include <hip/hip_runtime.h>
#include <hip/hip_bf16.h>

#define Hn   89
#define Tn   120
#define BM   128
#define LDP  104   // LDS row pitch (bf16): 208B -> 16B aligned, 2-way max bank alias
#define NTHR 768   // 12 waves = 6 j-slices x 2 row-halves; 1 block/CU

using bf16   = __bf16;
using bf16x4 = __attribute__((ext_vector_type(4))) __bf16;
using bf16x8 = __attribute__((ext_vector_type(8))) __bf16;
typedef __attribute__((ext_vector_type(4))) float f32x4;

__device__ __forceinline__ f32x4 ld4(const float* p) {   // 4B-aligned 16B load
  f32x4 v; __builtin_memcpy(&v, p, 16); return v;
}
__device__ __forceinline__ float fsig(float x) {
  return __builtin_amdgcn_rcpf(1.f + __builtin_amdgcn_exp2f(-1.44269504f * x));
}
__device__ __forceinline__ float ftanh(float x) {
  return 1.f - 2.f * __builtin_amdgcn_rcpf(1.f + __builtin_amdgcn_exp2f(2.88539008f * x));
}

// Persistent block: 128 batch rows x 120 steps, 12 waves all-compute.
// Wave (jt,hf): j-slice [16jt,16jt+16), rows [64hf, 64hf+64). Weights live in
// registers (B-frags); k==89 column carries biases (X/H col89 == 1.0).
// One barrier/step: { commit X(t), write h(t) -> buf[t&1]; BAR; issue X(t+1);
// MFMA + gates }. X(t+1) loads fly under the compute phase (post-barrier, so
// the pre-barrier vmcnt(0) drain doesn't serialize them).
__global__ __launch_bounds__(NTHR, 3)
void gru_fused(const float* __restrict__ X,    // [B][T][89]
               const float* __restrict__ Wih,  // [267][89]
               const float* __restrict__ Whh,  // [267][89]
               const float* __restrict__ bih,  // [267]
               const float* __restrict__ bhh,  // [267]
               const float* __restrict__ Wm,   // [32][89]
               const float* __restrict__ bm,   // [32]
               const float* __restrict__ Wo,   // [32]
               const float* __restrict__ bo,   // [1]
               float* __restrict__ Y,          // [B] mscore | [B][32] mmetric
               int Bt)
{
  __shared__ __align__(16) bf16 Xl[2][BM][LDP];
  __shared__ __align__(16) bf16 Hl[2][BM][LDP];
  __shared__ float Ml[BM][32];

  const int tid  = threadIdx.x;
  const int lane = tid & 63;
  const int wv   = tid >> 6;       // 0..11
  const int jt   = wv >> 1;        // j-slice 0..5
  const int hf   = wv & 1;         // row half
  const int l15  = lane & 15;
  const int kg   = lane >> 4;      // 0..3
  const int j    = jt * 16 + l15;  // 0..95; j==89 = constant-1 column
  const bool jok = (j < Hn);
  const size_t brow0 = (size_t)blockIdx.x * BM;

  // ---- weights -> persistent register B-frags; k==89 carries biases ----
  bf16x8 Bf[3][2][3];  // [gate r/z/n][ih/hh][k-tile]
#pragma unroll
  for (int g = 0; g < 3; ++g)
#pragma unroll
    for (int s = 0; s < 2; ++s) {
      const float* W = s ? Whh : Wih;
#pragma unroll
      for (int kt = 0; kt < 3; ++kt) {
        bf16x8 f;
        const int k0 = kt * 32 + kg * 8;
#pragma unroll
        for (int e = 0; e < 8; ++e) {
          const int k = k0 + e;
          float v = 0.f;
          if (jok) {
            if (k < Hn) v = W[(size_t)(g * Hn + j) * Hn + k];
            else if (k == Hn) {           // pairs with the 1.0 at col 89
              if (g < 2) v = s ? 0.f : (bih[g * Hn + j] + bhh[g * Hn + j]);
              else       v = s ? bhh[2 * Hn + j] : bih[2 * Hn + j];
            }
          }
          f[e] = (bf16)v;
        }
        Bf[g][s][kt] = f;
      }
    }

  // ---- X staging: 128 rows x 23 f32x4 chunks (chunk 22 = {x88,1,0,0}) ----
  int soff[4], loff[4];
  bool val[4], lst[4];
#pragma unroll
  for (int i = 0; i < 4; ++i) {
    const int p = tid + i * NTHR;        // 0..3071; 2944 used
    const int r = p / 23, s = p - r * 23;
    val[i]  = (p < BM * 23);
    lst[i]  = (s == 22);
    soff[i] = r * (Tn * Hn) + s * 4;
    loff[i] = r * LDP + s * 4;
  }
  const float* Xb2 = X + brow0 * (size_t)(Tn * Hn);
  f32x4 pa[4];

  auto issue = [&](int tHv) {
#pragma unroll
    for (int i = 0; i < 4; ++i) {
      if (val[i]) {
        if (lst[i]) { f32x4 v = {Xb2[soff[i] + tHv], 1.0f, 0.f, 0.f}; pa[i] = v; }
        else          pa[i] = ld4(Xb2 + soff[i] + tHv);
      }
    }
  };

  // ---- init pads (once): H col89=1.0, cols90..95=0; X cols92..95=0 ----
  if (tid < 2 * BM) {
    const int bb = tid >> 7, r = tid & (BM - 1);
    Hl[bb][r][89] = (bf16)1.0f;
#pragma unroll
    for (int c = 90; c < 96; ++c) Hl[bb][r][c] = (bf16)0.f;
#pragma unroll
    for (int c = 92; c < 96; ++c) Xl[bb][r][c] = (bf16)0.f;
  }

  float hold[4][4];
#pragma unroll
  for (int mt = 0; mt < 4; ++mt)
#pragma unroll
    for (int q = 0; q < 4; ++q) hold[mt][q] = 0.f;

  bf16*       hwb = &Hl[0][0][0] + (hf * 64 + kg * 4) * LDP + j;
  const bf16* xrb = &Xl[0][0][0] + (hf * 64 + l15) * LDP + kg * 8;
  const bf16* hrb = &Hl[0][0][0] + (hf * 64 + l15) * LDP + kg * 8;
  const int bufo = BM * LDP;

  issue(0);
  int tH = 0;
  for (int t = 0; t < Tn; ++t) {
    const int b = t & 1;
    // ---- commit X(t) regs -> buf b ----
#pragma unroll
    for (int i = 0; i < 4; ++i) {
      if (val[i]) {
        bf16x4 w;
        w[0] = (bf16)pa[i][0]; w[1] = (bf16)pa[i][1];
        w[2] = (bf16)pa[i][2]; w[3] = (bf16)pa[i][3];
        *(bf16x4*)(&Xl[b][0][0] + loff[i]) = w;
      }
    }
    // ---- write h(t) -> buf b (h(0)=0) ----
    if (jok) {
      bf16* hw = hwb + b * bufo;
#pragma unroll
      for (int mt = 0; mt < 4; ++mt)
#pragma unroll
        for (int q = 0; q < 4; ++q)
          hw[(mt * 16 + q) * LDP] = (bf16)hold[mt][q];
    }
    __syncthreads();
    tH += Hn;
    if (t + 1 < Tn) issue(tH);   // loads fly under this step's compute

    // ---- consume buf b: MFMA + gates ----
    const bf16* xr = xrb + b * bufo;
    const bf16* hr = hrb + b * bufo;
#pragma unroll
    for (int mt = 0; mt < 4; ++mt) {
      f32x4 ar = {0,0,0,0}, az = {0,0,0,0}, ain = {0,0,0,0}, ahn = {0,0,0,0};
#pragma unroll
      for (int kt = 0; kt < 3; ++kt) {
        const bf16x8 ax = *(const bf16x8*)(xr + mt * 16 * LDP + kt * 32);
        const bf16x8 ah = *(const bf16x8*)(hr + mt * 16 * LDP + kt * 32);
        ar  = __builtin_amdgcn_mfma_f32_16x16x32_bf16(ax, Bf[0][0][kt], ar, 0, 0, 0);
        ar  = __builtin_amdgcn_mfma_f32_16x16x32_bf16(ah, Bf[0][1][kt], ar, 0, 0, 0);
        az  = __builtin_amdgcn_mfma_f32_16x16x32_bf16(ax, Bf[1][0][kt], az, 0, 0, 0);
        az  = __builtin_amdgcn_mfma_f32_16x16x32_bf16(ah, Bf[1][1][kt], az, 0, 0, 0);
        ain = __builtin_amdgcn_mfma_f32_16x16x32_bf16(ax, Bf[2][0][kt], ain, 0, 0, 0);
        ahn = __builtin_amdgcn_mfma_f32_16x16x32_bf16(ah, Bf[2][1][kt], ahn, 0, 0, 0);
      }
#pragma unroll
      for (int q = 0; q < 4; ++q) {
        const float r_ = fsig(ar[q]);
        const float z_ = fsig(az[q]);
        const float n_ = ftanh(ain[q] + r_ * ahn[q]);
        hold[mt][q] = n_ + z_ * (hold[mt][q] - n_);
      }
    }
  }

  // ---- final h -> buf0 (t=119 consumed buf1; buf0 free) ----
  if (jok) {
#pragma unroll
    for (int mt = 0; mt < 4; ++mt)
#pragma unroll
      for (int q = 0; q < 4; ++q)
        hwb[(mt * 16 + q) * LDP] = (bf16)hold[mt][q];
  }
  __syncthreads();

  // ---- epilogue: metric_fc (89->32, sigmoid), output_fc (32->1, sigmoid) ----
  const bf16* Hf = &Hl[0][0][0];
  for (int p = tid; p < BM * 32; p += NTHR) {
    const int r = p >> 5, c = p & 31;
    float acc = bm[c];
    const bf16* hr2 = Hf + r * LDP;
    for (int k = 0; k < Hn; ++k) acc = fmaf((float)hr2[k], Wm[c * Hn + k], acc);
    const float mv = fsig(acc);
    Ml[r][c] = mv;
    Y[(size_t)Bt + (brow0 + r) * 32 + c] = mv;   // out_mmetric
  }
  __syncthreads();
  if (tid < BM) {
    float acc = bo[0];
#pragma unroll
    for (int c = 0; c < 32; ++c) acc = fmaf(Ml[tid][c], Wo[c], acc);
    Y[brow0 + tid] = fsig(acc);                  // out_mscore
  }
}

extern "C" void kernel_launch(void* const* d_in, const int* in_sizes, int n_in,
                              void* d_out, int out_size, void* d_ws, size_t ws_size,
                              hipStream_t stream) {
  const float* X   = (const float*)d_in[0];
  const float* Wih = (const float*)d_in[1];
  const float* Whh = (const float*)d_in[2];
  const float* bih = (const float*)d_in[3];
  const float* bhh = (const float*)d_in[4];
  const float* Wm  = (const float*)d_in[5];
  const float* bm  = (const float*)d_in[6];
  const float* Wo  = (const float*)d_in[7];
  const float* bo  = (const float*)d_in[8];

  const int B = in_sizes[0] / (Tn * Hn);   // 32768
  dim3 grid(B / BM), block(NTHR);
  gru_fused<<<grid, block, 0, stream>>>(X, Wih, Whh, bih, bhh, Wm, bm, Wo, bo,
                                        (float*)d_out, B);
}